// Round 14
// baseline (1224.658 us; speedup 1.0000x reference)
//
#include <hip/hip_runtime.h>
#include <cstdint>
#include <cstddef>

// Problem constants
#define HD 512      // hidden
#define BB 64       // batch
#define TT 64       // timesteps
#define VV 50257    // vocab
#define GG 2048     // 4*H
#define NBLK 128    // 2 branches * 2 btiles * 32 jblks (<=256 CUs -> co-resident)
#define NTHR 256    // 4 waves; wave = one GATE (q-split, register-resident weights)
#define PS 21       // P-exchange row stride (odd)
#define GCW 1024    // gather LDS chunk width (floats)
#define GR 4        // gather rows per block (16KB LDS -> 8 blocks/CU, R14)
#define VH 25136    // gather column-half size (2*VH >= VV)
#define SLOTSTRIDE 16  // barrier slot spacing in dwords (64B line per slot)

typedef __attribute__((ext_vector_type(8))) short bf16x8;   // 8 bf16 (4 VGPR)
typedef __attribute__((ext_vector_type(4))) float f32x4;

__device__ __forceinline__ float bf2f(unsigned short u) {
  union { unsigned int i; float f; } v; v.i = ((unsigned int)u) << 16; return v.f;
}
__device__ __forceinline__ unsigned short f2bf(float f) {
  union { float f; unsigned int i; } v; v.f = f;
  unsigned int r = (v.i + 0x7fffu + ((v.i >> 16) & 1u)) >> 16;   // RNE
  return (unsigned short)r;
}
__device__ __forceinline__ float sigf(float x) { return 1.0f / (1.0f + __expf(-x)); }

// Device-coherent 16B read (two 8B agent-scope bypass loads; proven R7-R13).
__device__ __forceinline__ bf16x8 ldh16(const unsigned short* p) {
  union { unsigned long long q[2]; bf16x8 v; } u;
  const unsigned long long* p64 = (const unsigned long long*)p;
  u.q[0] = __hip_atomic_load(p64,     __ATOMIC_RELAXED, __HIP_MEMORY_SCOPE_AGENT);
  u.q[1] = __hip_atomic_load(p64 + 1, __ATOMIC_RELAXED, __HIP_MEMORY_SCOPE_AGENT);
  return u.v;
}

// ---------------- detect: float dtype (fp32 vs bf16) and index width ----------------
__global__ void lstm_detect(const unsigned int* whh, const unsigned int* xq, int* flags) {
  __shared__ int csmall, oddnz;
  if (threadIdx.x == 0) { csmall = 0; oddnz = 0; }
  __syncthreads();
  {
    unsigned int w = whh[threadIdx.x];
    union { unsigned int i; float f; } lo; lo.i = w << 16;
    float a = fabsf(lo.f);
    if (a <= 0.0444f) atomicAdd(&csmall, 1);
  }
  if (threadIdx.x < 64) {
    if (xq[2 * threadIdx.x + 1] != 0) atomicAdd(&oddnz, 1);
  }
  __syncthreads();
  if (threadIdx.x == 0) {
    flags[0] = (csmall >= 240) ? 1 : 0;  // 1 => float inputs are bf16
    flags[1] = (oddnz == 0) ? 1 : 0;     // 1 => x is int64
  }
}

// ---------------- prep: biases, indices, h zero, barrier slots ----------------
struct PrepParams {
  const void* src[18];
  const int* flags;
  unsigned int* bar;     // 2048 uints: 4 groups x 32 slots x 16-dword stride
  int* xidx;             // [2][B*T]
  float* bsum0;          // [2][2048]
  float* bsum1;          // [2][2048]
  unsigned short* h0;    // [2][2][64][512]  bf16 ping-pong
  unsigned short* h1;    // [2][2][64][512]
};

__global__ void lstm_prep(PrepParams p) {
  const int F = p.flags[0];
  const int X = p.flags[1];
  const size_t NBS = (size_t)2 * 2 * GG;        // 8192
  const size_t NXI = (size_t)2 * BB * TT;       // 8192
  const size_t NHZ = 262144;                    // h0+h1 ushort count
  const size_t NBZ = 2048;                      // barrier slot dwords (8KB)
  const size_t TOT = NBS + NXI + NHZ + NBZ;
  for (size_t g = (size_t)blockIdx.x * blockDim.x + threadIdx.x; g < TOT;
       g += (size_t)gridDim.x * blockDim.x) {
    size_t e = g;
    if (e < NBS) {
      size_t br = e / (2 * GG), r = e % (2 * GG);
      size_t layer = r / GG, gg = r % GG;
      const void* s1 = p.src[(br ? 12 : 4) + (layer ? 4 : 0)];
      const void* s2 = p.src[(br ? 13 : 5) + (layer ? 4 : 0)];
      float v1 = F ? bf2f(((const unsigned short*)s1)[gg]) : ((const float*)s1)[gg];
      float v2 = F ? bf2f(((const unsigned short*)s2)[gg]) : ((const float*)s2)[gg];
      (layer ? p.bsum1 : p.bsum0)[br * GG + gg] = v1 + v2;
      continue;
    }
    e -= NBS;
    if (e < NXI) {
      size_t br = e / (BB * TT), r = e % (BB * TT);
      const void* s = p.src[br ? 1 : 0];
      p.xidx[e] = X ? ((const int*)s)[2 * r] : ((const int*)s)[r];
      continue;
    }
    e -= NXI;
    if (e < NHZ) {
      const size_t half = 131072;
      if (e < half) p.h0[e] = 0; else p.h1[e - half] = 0;
      continue;
    }
    e -= NHZ;
    p.bar[e] = 0;   // barrier slots reset every call (replay determinism)
  }
}

// ---------------- gather: x_proj[branch][t][b][g] = Wih0[g][ token[b,t] ] ----------
// R14: GR=4 rows, 16KB LDS, 8 blocks/CU (2048 blocks) -- 2x memory-level
// parallelism vs R13. One-chunk-ahead register prefetch retained.
struct GatherParams {
  const void* wih0[2];
  const int* xidx;       // [2][4096], b-major [b][t]
  void* xp;              // [branch][t][b][g] f32 or bf16
  const int* flags;
  int xp32;
};

__launch_bounds__(256, 8)
__global__ void lstm_gather(GatherParams gp) {
  __shared__ float lds[GR][GCW];   // 16 KB
  const int tid = threadIdx.x;
  const int branch = blockIdx.x >> 10;
  const int rem = blockIdx.x & 1023;
  const int gc = rem >> 1;          // 0..511
  const int half = rem & 1;
  const int g0 = gc * GR;
  const int cbase = half * VH;
  const int cend = (half ? VV : VH);
  const int F = gp.flags[0];
  const int XP = gp.xp32;
  const int t  = tid & 63;
  const int bq = tid >> 6;         // 0..3

  int tok[16];
  const int* xid = gp.xidx + branch * (BB * TT);
#pragma unroll
  for (int i = 0; i < 16; ++i) tok[i] = xid[(bq * 16 + i) * TT + t];

  float* xpf = (float*)gp.xp;
  unsigned short* xpb = (unsigned short*)gp.xp;

  float rg[GR][4];
  auto issue = [&](int c0, int cs) {
    if (F) {
      const unsigned short* w = (const unsigned short*)gp.wih0[branch];
#pragma unroll
      for (int r = 0; r < GR; ++r)
#pragma unroll
        for (int j = 0; j < 4; ++j) {
          const int c = tid + j * 256;
          rg[r][j] = (c < cs) ? bf2f(w[(size_t)(g0 + r) * VV + c0 + c]) : 0.f;
        }
    } else {
      const float* w = (const float*)gp.wih0[branch];
#pragma unroll
      for (int r = 0; r < GR; ++r)
#pragma unroll
        for (int j = 0; j < 4; ++j) {
          const int c = tid + j * 256;
          rg[r][j] = (c < cs) ? w[(size_t)(g0 + r) * VV + c0 + c] : 0.f;
        }
    }
  };

  int c0 = cbase;
  int cs = (cend - c0 < GCW) ? (cend - c0) : GCW;
  issue(c0, cs);
  for (;;) {
    // commit prefetched chunk to LDS
#pragma unroll
    for (int r = 0; r < GR; ++r)
#pragma unroll
      for (int j = 0; j < 4; ++j)
        lds[r][tid + j * 256] = rg[r][j];
    __syncthreads();

    const int c1 = c0 + GCW;
    const int cs1 = (c1 < cend) ? ((cend - c1 < GCW) ? (cend - c1) : GCW) : 0;
    if (cs1 > 0) issue(c1, cs1);   // prefetch next (hidden under scatter+sync)

    // scatter current chunk (4 g-values -> one f32x4 store)
#pragma unroll
    for (int i = 0; i < 16; ++i) {
      const unsigned int d = (unsigned int)(tok[i] - c0);
      if (d < (unsigned int)cs) {
        const int b = bq * 16 + i;
        const size_t base = (((size_t)branch * TT + t) * BB + b) * GG + g0;
        if (XP) {
          f32x4 x0 = { lds[0][d], lds[1][d], lds[2][d], lds[3][d] };
          *(f32x4*)(xpf + base) = x0;
        } else {
#pragma unroll
          for (int r = 0; r < GR; ++r) xpb[base + r] = f2bf(lds[r][d]);
        }
      }
    }
    __syncthreads();
    if (cs1 == 0) break;
    c0 = c1; cs = cs1;
  }
}

// ---------------- slot barrier: one 64B line per block, parallel poll (proven R8-R13) ----
__device__ __forceinline__ void gbar_slots(unsigned int* slots, int myslot,
                                           unsigned int target) {
  __syncthreads();
  if (threadIdx.x < 64) {
    if (threadIdx.x == 0) {
      asm volatile("" ::: "memory");
      __hip_atomic_fetch_add(&slots[myslot * SLOTSTRIDE], 1u,
                             __ATOMIC_RELAXED, __HIP_MEMORY_SCOPE_AGENT);
    }
    const int lane = threadIdx.x;
    bool done;
    do {
      unsigned int v = target;
      if (lane < 32)
        v = __hip_atomic_load(&slots[lane * SLOTSTRIDE],
                              __ATOMIC_RELAXED, __HIP_MEMORY_SCOPE_AGENT);
      done = __all(v >= target);
      if (!done) __builtin_amdgcn_s_sleep(1);
    } while (!done);
    asm volatile("" ::: "memory");
  }
  __syncthreads();
}

// ---------------- main kernel (128 blocks co-resident; byte-identical to R13) -------
struct LstmParams {
  const void* xp;        // x_proj [branch][t][b][g]
  const float* bsum0;
  const float* bsum1;
  const void* whh0[2];   // [2048][512]
  const void* wih1[2];   // [2048][512]
  const void* whh1[2];   // [2048][512]
  unsigned short* h0;
  unsigned short* h1;
  unsigned int* bar;     // 4 groups x 32 slots x SLOTSTRIDE dwords
  const int* flags;
  int xp32;
  void* out;
};

__launch_bounds__(NTHR, 1)
__global__ void lstm_main(LstmParams p) {
  __shared__ float P0[4][32][PS];
  __shared__ float P1[4][32][PS];
  __shared__ __attribute__((aligned(16))) unsigned short h0s[32 * 512]; // 32 KB
  __shared__ __attribute__((aligned(16))) unsigned short h1s[32 * 512]; // 32 KB

  const int tid  = threadIdx.x;
  const int l15  = tid & 15;
  const int lk   = (tid & 63) >> 4; // k-group within wave (0..3)
  const int wid  = tid >> 6;        // wave = gate q (0..3)

  // XCD-aware decomposition (performance heuristic only)
  const int bid  = blockIdx.x;
  const int xcd  = bid & 7;
  const int rest = bid >> 3;                 // 0..15
  const int brr  = (xcd >= 4) ? 1 : 0;
  const int u    = (xcd & 3) + rest * 4;     // 0..63
  const int btile = u & 1;
  const int jblk  = u >> 1;                  // 0..31
  const int jcol  = jblk * 16 + l15;
  const int F = p.flags[0];
  const int XP = p.xp32;

  unsigned short* h0b = p.h0 + (size_t)brr * 2 * BB * HD;
  unsigned short* h1b = p.h1 + (size_t)brr * 2 * BB * HD;
  const float* xpf = (const float*)p.xp;
  const unsigned short* xpb = (const unsigned short*)p.xp;
  unsigned int* slots = p.bar + (brr * 2 + btile) * 32 * SLOTSTRIDE;

  // ---- register-resident weights, loaded DIRECTLY from inputs (R13)
  auto ldw8 = [&](const void* srcp, size_t eoff) -> bf16x8 {
    if (F) return *(const bf16x8*)((const unsigned short*)srcp + eoff);
    const float* f = (const float*)srcp + eoff;
    f32x4 a = *(const f32x4*)f;
    f32x4 b = *(const f32x4*)(f + 4);
    bf16x8 r;
    r[0] = (short)f2bf(a[0]); r[1] = (short)f2bf(a[1]);
    r[2] = (short)f2bf(a[2]); r[3] = (short)f2bf(a[3]);
    r[4] = (short)f2bf(b[0]); r[5] = (short)f2bf(b[1]);
    r[6] = (short)f2bf(b[2]); r[7] = (short)f2bf(b[3]);
    return r;
  };
  bf16x8 bw0[16], bw1[32];
  {
    const size_t grow = (size_t)(wid * HD + jcol);   // gate row 0..2047
#pragma unroll
    for (int kc = 0; kc < 16; ++kc)
      bw0[kc] = ldw8(p.whh0[brr], grow * 512 + kc * 32 + lk * 8);
#pragma unroll
    for (int kc = 0; kc < 16; ++kc)
      bw1[kc] = ldw8(p.wih1[brr], grow * 512 + kc * 32 + lk * 8);
#pragma unroll
    for (int kc = 16; kc < 32; ++kc)
      bw1[kc] = ldw8(p.whh1[brr], grow * 512 + (kc - 16) * 32 + lk * 8);
  }

  // ---- staging role: thread stages row rls = tid>>3; 8 chunks of 16B
  const int rls = tid >> 3;
  const int seg = tid & 7;
  const int growl = btile * 32 + rls;    // global batch row staged by this thread

  // ---- update role: threads 0..127, each owns 1 row x 4 consecutive cols
  const bool upd = (tid < 128);
  const int rl   = tid >> 2;            // local row 0..31 (for upd threads)
  const int uq4  = (tid & 3) * 4;       // col offset within jblk's 16
  const int ucol = jblk * 16 + uq4;     // global col base (4 cols)
  const int ub   = btile * 32 + rl;     // global batch row

  float bs0q[16], bs1q[16];
  if (upd) {
#pragma unroll
    for (int q = 0; q < 4; ++q)
#pragma unroll
      for (int j = 0; j < 4; ++j) {
        bs0q[q * 4 + j] = p.bsum0[brr * GG + q * HD + ucol + j];
        bs1q[q * 4 + j] = p.bsum1[brr * GG + q * HD + ucol + j];
      }
  }

  float c0[4] = {0.f, 0.f, 0.f, 0.f}, c1[4] = {0.f, 0.f, 0.f, 0.f};
  float xgc[16], xgn[16];
  unsigned int dummy = 0;

  auto xoff = [&](int t, int q) -> size_t {
    return (((size_t)brr * TT + t) * BB + ub) * GG + (size_t)q * HD + ucol;
  };
  if (upd) {
#pragma unroll
    for (int q = 0; q < 4; ++q) {
      if (XP) {
        f32x4 v = *(const f32x4*)(xpf + xoff(0, q));
#pragma unroll
        for (int j = 0; j < 4; ++j) xgc[q * 4 + j] = v[j];
      } else {
#pragma unroll
        for (int j = 0; j < 4; ++j) xgc[q * 4 + j] = bf2f(xpb[xoff(0, q) + j]);
      }
    }
  }

  // swizzled LDS fragment readers (byte ^= (row&7)<<4; write side uses same XOR)
  auto frag0 = [&](int rloc, int e0) -> bf16x8 {
    const int be = (e0 * 2) ^ ((rloc & 7) << 4);
    return *(const bf16x8*)&h0s[rloc * 512 + (be >> 1)];
  };
  auto frag1 = [&](int rloc, int e0) -> bf16x8 {
    const int be = (e0 * 2) ^ ((rloc & 7) << 4);
    return *(const bf16x8*)&h1s[rloc * 512 + (be >> 1)];
  };

  for (int s = 0; s <= TT; ++s) {
    const unsigned short* h0r = h0b + (size_t)((s + 1) & 1) * BB * HD; // h0_{s-1}
    const unsigned short* h1p = h1b + (size_t)(s & 1) * BB * HD;       // h1_{s-2}
    const bool do0 = (s < TT), do1 = (s >= 1);

    // ---- stage h tiles ONCE per block (bypass loads -> swizzled LDS; R10 schedule)
    {
      const unsigned short* s0 = h0r + (size_t)growl * HD;
      const unsigned short* s1 = h1p + (size_t)growl * HD;
      bf16x8 sv0[8], sv1[8];
#pragma unroll
      for (int c = 0; c < 8; ++c) {
        sv0[c] = ldh16(s0 + c * 64 + seg * 8);
        sv1[c] = ldh16(s1 + c * 64 + seg * 8);
      }
#pragma unroll
      for (int c = 0; c < 8; ++c) {
        const int be = ((c * 8 + seg) * 16) ^ ((rls & 7) << 4);
        *(bf16x8*)&h0s[rls * 512 + (be >> 1)] = sv0[c];
        *(bf16x8*)&h1s[rls * 512 + (be >> 1)] = sv1[c];
      }
    }

    // prefetch x_proj for next step (independent of staging)
    if (upd) {
      int tn = s + 1; if (tn > TT - 1) tn = TT - 1;
#pragma unroll
      for (int q = 0; q < 4; ++q) {
        if (XP) {
          f32x4 v = *(const f32x4*)(xpf + xoff(tn, q));
#pragma unroll
          for (int j = 0; j < 4; ++j) xgn[q * 4 + j] = v[j];
        } else {
#pragma unroll
          for (int j = 0; j < 4; ++j) xgn[q * 4 + j] = bf2f(xpb[xoff(tn, q) + j]);
        }
      }
    }
    __syncthreads();   // staged tiles visible

    if (do0) {  // layer 0, time s: P0[q] = h0_{s-1}[btile rows] @ W0[q-slice]^T
      f32x4 acc0[2];
#pragma unroll
      for (int bt = 0; bt < 2; ++bt) acc0[bt] = (f32x4){0.f, 0.f, 0.f, 0.f};
#pragma unroll
      for (int kc = 0; kc < 16; ++kc) {
        const int k0 = kc * 32 + lk * 8;
#pragma unroll
        for (int bt = 0; bt < 2; ++bt) {
          bf16x8 av = frag0(bt * 16 + l15, k0);
          acc0[bt] = __builtin_amdgcn_mfma_f32_16x16x32_bf16(av, bw0[kc], acc0[bt], 0, 0, 0);
        }
      }
#pragma unroll
      for (int bt = 0; bt < 2; ++bt)
#pragma unroll
        for (int i = 0; i < 4; ++i)
          P0[wid][bt * 16 + lk * 4 + i][l15] = acc0[bt][i];
    }
    if (do1) {  // layer 1, time s-1: P1[q] = [h0_{s-1} | h1_{s-2}] @ W1[q-slice]^T
      f32x4 acc1[2];
#pragma unroll
      for (int bt = 0; bt < 2; ++bt) acc1[bt] = (f32x4){0.f, 0.f, 0.f, 0.f};
#pragma unroll
      for (int kc = 0; kc < 32; ++kc) {
        const int k0 = kc * 32 + lk * 8;
#pragma unroll
        for (int bt = 0; bt < 2; ++bt) {
          bf16x8 av = (kc < 16) ? frag0(bt * 16 + l15, k0)
                                : frag1(bt * 16 + l15, k0 - 512);
          acc1[bt] = __builtin_amdgcn_mfma_f32_16x16x32_bf16(av, bw1[kc], acc1[bt], 0, 0, 0);
        }
      }
#pragma unroll
      for (int bt = 0; bt < 2; ++bt)
#pragma unroll
        for (int i = 0; i < 4; ++i)
          P1[wid][bt * 16 + lk * 4 + i][l15] = acc1[bt][i];
    }
    __syncthreads();

    if (do0 && upd) {  // layer-0 cell update: 1 row x 4 cols -> one 64-bit swap
      unsigned short* h0w = h0b + (size_t)(s & 1) * BB * HD;
      unsigned long long pk = 0ull;
#pragma unroll
      for (int j = 0; j < 4; ++j) {
        float gi = sigf(P0[0][rl][uq4 + j] + bs0q[0 + j] + xgc[0 + j]);
        float gf = sigf(P0[1][rl][uq4 + j] + bs0q[4 + j] + xgc[4 + j]);
        float gc = tanhf(P0[2][rl][uq4 + j] + bs0q[8 + j] + xgc[8 + j]);
        float go = sigf(P0[3][rl][uq4 + j] + bs0q[12 + j] + xgc[12 + j]);
        c0[j] = gf * c0[j] + gi * gc;
        float hv = go * tanhf(c0[j]);
        pk |= (unsigned long long)f2bf(hv) << (16 * j);
      }
      unsigned long long* dst =
          (unsigned long long*)(h0w + (size_t)ub * HD + ucol);
      unsigned long long old =
          __hip_atomic_exchange(dst, pk, __ATOMIC_RELAXED, __HIP_MEMORY_SCOPE_AGENT);
      dummy ^= (unsigned int)(old ^ (old >> 32));
    }
    if (do1 && upd) {  // layer-1 cell update + output write
      unsigned short* h1w = h1b + (size_t)((s - 1) & 1) * BB * HD;
      const int tl = s - 1;
      unsigned long long pk = 0ull;
      float hv4[4];
#pragma unroll
      for (int j = 0; j < 4; ++j) {
        float gi = sigf(P1[0][rl][uq4 + j] + bs1q[0 + j]);
        float gf = sigf(P1[1][rl][uq4 + j] + bs1q[4 + j]);
        float gc = tanhf(P1[2][rl][uq4 + j] + bs1q[8 + j]);
        float go = sigf(P1[3][rl][uq4 + j] + bs1q[12 + j]);
        c1[j] = gf * c1[j] + gi * gc;
        hv4[j] = go * tanhf(c1[j]);
        pk |= (unsigned long long)f2bf(hv4[j]) << (16 * j);
      }
      unsigned long long* dst =
          (unsigned long long*)(h1w + (size_t)ub * HD + ucol);
      unsigned long long old =
          __hip_atomic_exchange(dst, pk, __ATOMIC_RELAXED, __HIP_MEMORY_SCOPE_AGENT);
      dummy ^= (unsigned int)(old ^ (old >> 32));
      const size_t oo = (((size_t)brr * BB + ub) * TT + tl) * HD + ucol;
      if (F) {
        *(unsigned long long*)((unsigned short*)p.out + oo) = pk;
      } else {
        f32x4 v = { hv4[0], hv4[1], hv4[2], hv4[3] };
        *(f32x4*)((float*)p.out + oo) = v;
      }
    }

    if (upd) {
#pragma unroll
      for (int i2 = 0; i2 < 16; ++i2) xgc[i2] = xgn[i2];
    }

    if (s < TT) gbar_slots(slots, jblk, (unsigned int)(s + 1));
  }

  if (dummy == 0x9E3779B9u) p.bar[2047] = dummy;  // consume swap returns (never taken)
}

// ---------------- host ----------------
extern "C" void kernel_launch(void* const* d_in, const int* in_sizes, int n_in,
                              void* d_out, int out_size, void* d_ws, size_t ws_size,
                              hipStream_t stream) {
  if (n_in < 18) return;
  char* ws = (char*)d_ws;
  size_t off = 0;
  auto alloc = [&](size_t bytes) -> void* {
    off = (off + 255) & ~(size_t)255;
    void* r = ws + off;
    off += bytes;
    return r;
  };
  int* flags           = (int*)alloc(256);
  unsigned int* bar    = (unsigned int*)alloc(8192);
  int* xidx            = (int*)alloc((size_t)2 * BB * TT * 4);
  float* bsum0         = (float*)alloc((size_t)2 * GG * 4);
  float* bsum1         = (float*)alloc((size_t)2 * GG * 4);
  unsigned short* h0   = (unsigned short*)alloc((size_t)2 * 2 * BB * HD * 2);
  unsigned short* h1   = (unsigned short*)alloc((size_t)2 * 2 * BB * HD * 2);

  const size_t xp_f32_bytes = (size_t)2 * TT * BB * GG * 4;   // 67.1 MB
  const size_t xp_b16_bytes = (size_t)2 * TT * BB * GG * 2;   // 33.6 MB
  int xp32 = (off + 256 + xp_f32_bytes <= ws_size) ? 1 : 0;
  void* xp = alloc(xp32 ? xp_f32_bytes : xp_b16_bytes);
  (void)in_sizes; (void)out_size;

  lstm_detect<<<dim3(1), dim3(256), 0, stream>>>(
      (const unsigned int*)d_in[3], (const unsigned int*)d_in[0], flags);

  PrepParams pp;
  for (int i = 0; i < 18; ++i) pp.src[i] = d_in[i];
  pp.flags = flags; pp.bar = bar; pp.xidx = xidx;
  pp.bsum0 = bsum0; pp.bsum1 = bsum1;
  pp.h0 = h0; pp.h1 = h1;
  lstm_prep<<<dim3(256), dim3(256), 0, stream>>>(pp);

  GatherParams gp;
  gp.wih0[0] = d_in[2]; gp.wih0[1] = d_in[10];
  gp.xidx = xidx; gp.xp = xp; gp.flags = flags; gp.xp32 = xp32;
  lstm_gather<<<dim3(2048), dim3(256), 0, stream>>>(gp);

  LstmParams lp;
  lp.xp = xp; lp.bsum0 = bsum0; lp.bsum1 = bsum1;
  lp.whh0[0] = d_in[3];  lp.whh0[1] = d_in[11];
  lp.wih1[0] = d_in[6];  lp.wih1[1] = d_in[14];
  lp.whh1[0] = d_in[7];  lp.whh1[1] = d_in[15];
  lp.h0 = h0; lp.h1 = h1;
  lp.bar = bar; lp.flags = flags; lp.xp32 = xp32; lp.out = d_out;
  lstm_main<<<dim3(NBLK), dim3(NTHR), 0, stream>>>(lp);
}

// Round 15
// 803.188 us; speedup vs baseline: 1.5247x; 1.5247x over previous
//
#include <hip/hip_runtime.h>
#include <cstdint>
#include <cstddef>

// Problem constants
#define HD 512      // hidden
#define BB 64       // batch
#define TT 64       // timesteps
#define VV 50257    // vocab
#define GG 2048     // 4*H
#define NBLK 128    // 2 branches * 2 btiles * 32 jblks (<=256 CUs -> co-resident)
#define NTHR 256    // 4 waves; wave = one GATE (q-split, register-resident weights)
#define PS 21       // P-exchange row stride (odd)
#define GCW 1024    // gather LDS chunk width (floats)
#define GR 16       // gather rows per block (64KB LDS, 2 blocks/CU; 64B stores --
                    // R14 lesson: scattered-store HBM bill = blocks x hits x ~128B
                    // granule, so FEWER blocks + WIDER stores wins)
#define VH 25136    // gather column-half size (2*VH >= VV)
#define SLOTSTRIDE 16  // barrier slot spacing in dwords (64B line per slot)

typedef __attribute__((ext_vector_type(8))) short bf16x8;   // 8 bf16 (4 VGPR)
typedef __attribute__((ext_vector_type(4))) float f32x4;

__device__ __forceinline__ float bf2f(unsigned short u) {
  union { unsigned int i; float f; } v; v.i = ((unsigned int)u) << 16; return v.f;
}
__device__ __forceinline__ unsigned short f2bf(float f) {
  union { float f; unsigned int i; } v; v.f = f;
  unsigned int r = (v.i + 0x7fffu + ((v.i >> 16) & 1u)) >> 16;   // RNE
  return (unsigned short)r;
}
__device__ __forceinline__ float sigf(float x) { return 1.0f / (1.0f + __expf(-x)); }

// Device-coherent 16B read (two 8B agent-scope bypass loads; proven R7-R14).
__device__ __forceinline__ bf16x8 ldh16(const unsigned short* p) {
  union { unsigned long long q[2]; bf16x8 v; } u;
  const unsigned long long* p64 = (const unsigned long long*)p;
  u.q[0] = __hip_atomic_load(p64,     __ATOMIC_RELAXED, __HIP_MEMORY_SCOPE_AGENT);
  u.q[1] = __hip_atomic_load(p64 + 1, __ATOMIC_RELAXED, __HIP_MEMORY_SCOPE_AGENT);
  return u.v;
}

// ---------------- detect: float dtype (fp32 vs bf16) and index width ----------------
__global__ void lstm_detect(const unsigned int* whh, const unsigned int* xq, int* flags) {
  __shared__ int csmall, oddnz;
  if (threadIdx.x == 0) { csmall = 0; oddnz = 0; }
  __syncthreads();
  {
    unsigned int w = whh[threadIdx.x];
    union { unsigned int i; float f; } lo; lo.i = w << 16;
    float a = fabsf(lo.f);
    if (a <= 0.0444f) atomicAdd(&csmall, 1);
  }
  if (threadIdx.x < 64) {
    if (xq[2 * threadIdx.x + 1] != 0) atomicAdd(&oddnz, 1);
  }
  __syncthreads();
  if (threadIdx.x == 0) {
    flags[0] = (csmall >= 240) ? 1 : 0;  // 1 => float inputs are bf16
    flags[1] = (oddnz == 0) ? 1 : 0;     // 1 => x is int64
  }
}

// ---------------- prep: biases, indices, h zero, barrier slots ----------------
struct PrepParams {
  const void* src[18];
  const int* flags;
  unsigned int* bar;     // 2048 uints: 4 groups x 32 slots x 16-dword stride
  int* xidx;             // [2][B*T]
  float* bsum0;          // [2][2048]
  float* bsum1;          // [2][2048]
  unsigned short* h0;    // [2][2][64][512]  bf16 ping-pong
  unsigned short* h1;    // [2][2][64][512]
};

__global__ void lstm_prep(PrepParams p) {
  const int F = p.flags[0];
  const int X = p.flags[1];
  const size_t NBS = (size_t)2 * 2 * GG;        // 8192
  const size_t NXI = (size_t)2 * BB * TT;       // 8192
  const size_t NHZ = 262144;                    // h0+h1 ushort count
  const size_t NBZ = 2048;                      // barrier slot dwords (8KB)
  const size_t TOT = NBS + NXI + NHZ + NBZ;
  for (size_t g = (size_t)blockIdx.x * blockDim.x + threadIdx.x; g < TOT;
       g += (size_t)gridDim.x * blockDim.x) {
    size_t e = g;
    if (e < NBS) {
      size_t br = e / (2 * GG), r = e % (2 * GG);
      size_t layer = r / GG, gg = r % GG;
      const void* s1 = p.src[(br ? 12 : 4) + (layer ? 4 : 0)];
      const void* s2 = p.src[(br ? 13 : 5) + (layer ? 4 : 0)];
      float v1 = F ? bf2f(((const unsigned short*)s1)[gg]) : ((const float*)s1)[gg];
      float v2 = F ? bf2f(((const unsigned short*)s2)[gg]) : ((const float*)s2)[gg];
      (layer ? p.bsum1 : p.bsum0)[br * GG + gg] = v1 + v2;
      continue;
    }
    e -= NBS;
    if (e < NXI) {
      size_t br = e / (BB * TT), r = e % (BB * TT);
      const void* s = p.src[br ? 1 : 0];
      p.xidx[e] = X ? ((const int*)s)[2 * r] : ((const int*)s)[r];
      continue;
    }
    e -= NXI;
    if (e < NHZ) {
      const size_t half = 131072;
      if (e < half) p.h0[e] = 0; else p.h1[e - half] = 0;
      continue;
    }
    e -= NHZ;
    p.bar[e] = 0;   // barrier slots reset every call (replay determinism)
  }
}

// ---------------- gather: x_proj[branch][t][b][g] = Wih0[g][ token[b,t] ] ----------
// R15: GR=16 rows/block, 512 blocks (2/CU), one-chunk-ahead register prefetch,
// 64B-contiguous store per hit. Write bill = blocks/branch x 4096 x granule.
struct GatherParams {
  const void* wih0[2];
  const int* xidx;       // [2][4096], b-major [b][t]
  void* xp;              // [branch][t][b][g] f32 or bf16
  const int* flags;
  int xp32;
};

__launch_bounds__(256, 2)
__global__ void lstm_gather(GatherParams gp) {
  __shared__ float lds[GR][GCW];   // 64 KB
  const int tid = threadIdx.x;
  const int branch = blockIdx.x >> 8;
  const int rem = blockIdx.x & 255;
  const int gc = rem >> 1;          // 0..127
  const int half = rem & 1;
  const int g0 = gc * GR;
  const int cbase = half * VH;
  const int cend = (half ? VV : VH);
  const int F = gp.flags[0];
  const int XP = gp.xp32;
  const int t  = tid & 63;
  const int bq = tid >> 6;         // 0..3

  int tok[16];
  const int* xid = gp.xidx + branch * (BB * TT);
#pragma unroll
  for (int i = 0; i < 16; ++i) tok[i] = xid[(bq * 16 + i) * TT + t];

  float* xpf = (float*)gp.xp;
  unsigned short* xpb = (unsigned short*)gp.xp;

  float rg[GR][4];
  auto issue = [&](int c0, int cs) {
    if (F) {
      const unsigned short* w = (const unsigned short*)gp.wih0[branch];
#pragma unroll
      for (int r = 0; r < GR; ++r)
#pragma unroll
        for (int j = 0; j < 4; ++j) {
          const int c = tid + j * 256;
          rg[r][j] = (c < cs) ? bf2f(w[(size_t)(g0 + r) * VV + c0 + c]) : 0.f;
        }
    } else {
      const float* w = (const float*)gp.wih0[branch];
#pragma unroll
      for (int r = 0; r < GR; ++r)
#pragma unroll
        for (int j = 0; j < 4; ++j) {
          const int c = tid + j * 256;
          rg[r][j] = (c < cs) ? w[(size_t)(g0 + r) * VV + c0 + c] : 0.f;
        }
    }
  };

  int c0 = cbase;
  int cs = (cend - c0 < GCW) ? (cend - c0) : GCW;
  issue(c0, cs);
  for (;;) {
    // commit prefetched chunk to LDS
#pragma unroll
    for (int r = 0; r < GR; ++r)
#pragma unroll
      for (int j = 0; j < 4; ++j)
        lds[r][tid + j * 256] = rg[r][j];
    __syncthreads();

    const int c1 = c0 + GCW;
    const int cs1 = (c1 < cend) ? ((cend - c1 < GCW) ? (cend - c1) : GCW) : 0;
    if (cs1 > 0) issue(c1, cs1);   // prefetch next (hidden under scatter+sync)

    // scatter current chunk: 16 g-values -> 64B contiguous store per hit
#pragma unroll
    for (int i = 0; i < 16; ++i) {
      const unsigned int d = (unsigned int)(tok[i] - c0);
      if (d < (unsigned int)cs) {
        const int b = bq * 16 + i;
        const size_t base = (((size_t)branch * TT + t) * BB + b) * GG + g0;
        if (XP) {
#pragma unroll
          for (int v = 0; v < 4; ++v) {
            f32x4 x = { lds[v*4+0][d], lds[v*4+1][d], lds[v*4+2][d], lds[v*4+3][d] };
            *(f32x4*)(xpf + base + v * 4) = x;
          }
        } else {
#pragma unroll
          for (int r = 0; r < GR; ++r) xpb[base + r] = f2bf(lds[r][d]);
        }
      }
    }
    __syncthreads();
    if (cs1 == 0) break;
    c0 = c1; cs = cs1;
  }
}

// ---------------- slot barrier: one 64B line per block, parallel poll (proven R8-R14) ----
__device__ __forceinline__ void gbar_slots(unsigned int* slots, int myslot,
                                           unsigned int target) {
  __syncthreads();
  if (threadIdx.x < 64) {
    if (threadIdx.x == 0) {
      asm volatile("" ::: "memory");
      __hip_atomic_fetch_add(&slots[myslot * SLOTSTRIDE], 1u,
                             __ATOMIC_RELAXED, __HIP_MEMORY_SCOPE_AGENT);
    }
    const int lane = threadIdx.x;
    bool done;
    do {
      unsigned int v = target;
      if (lane < 32)
        v = __hip_atomic_load(&slots[lane * SLOTSTRIDE],
                              __ATOMIC_RELAXED, __HIP_MEMORY_SCOPE_AGENT);
      done = __all(v >= target);
      if (!done) __builtin_amdgcn_s_sleep(1);
    } while (!done);
    asm volatile("" ::: "memory");
  }
  __syncthreads();
}

// ---------------- main kernel (128 blocks co-resident; byte-identical to R13) -------
struct LstmParams {
  const void* xp;        // x_proj [branch][t][b][g]
  const float* bsum0;
  const float* bsum1;
  const void* whh0[2];   // [2048][512]
  const void* wih1[2];   // [2048][512]
  const void* whh1[2];   // [2048][512]
  unsigned short* h0;
  unsigned short* h1;
  unsigned int* bar;     // 4 groups x 32 slots x SLOTSTRIDE dwords
  const int* flags;
  int xp32;
  void* out;
};

__launch_bounds__(NTHR, 1)
__global__ void lstm_main(LstmParams p) {
  __shared__ float P0[4][32][PS];
  __shared__ float P1[4][32][PS];
  __shared__ __attribute__((aligned(16))) unsigned short h0s[32 * 512]; // 32 KB
  __shared__ __attribute__((aligned(16))) unsigned short h1s[32 * 512]; // 32 KB

  const int tid  = threadIdx.x;
  const int l15  = tid & 15;
  const int lk   = (tid & 63) >> 4; // k-group within wave (0..3)
  const int wid  = tid >> 6;        // wave = gate q (0..3)

  // XCD-aware decomposition (performance heuristic only)
  const int bid  = blockIdx.x;
  const int xcd  = bid & 7;
  const int rest = bid >> 3;                 // 0..15
  const int brr  = (xcd >= 4) ? 1 : 0;
  const int u    = (xcd & 3) + rest * 4;     // 0..63
  const int btile = u & 1;
  const int jblk  = u >> 1;                  // 0..31
  const int jcol  = jblk * 16 + l15;
  const int F = p.flags[0];
  const int XP = p.xp32;

  unsigned short* h0b = p.h0 + (size_t)brr * 2 * BB * HD;
  unsigned short* h1b = p.h1 + (size_t)brr * 2 * BB * HD;
  const float* xpf = (const float*)p.xp;
  const unsigned short* xpb = (const unsigned short*)p.xp;
  unsigned int* slots = p.bar + (brr * 2 + btile) * 32 * SLOTSTRIDE;

  // ---- register-resident weights, loaded DIRECTLY from inputs (R13)
  auto ldw8 = [&](const void* srcp, size_t eoff) -> bf16x8 {
    if (F) return *(const bf16x8*)((const unsigned short*)srcp + eoff);
    const float* f = (const float*)srcp + eoff;
    f32x4 a = *(const f32x4*)f;
    f32x4 b = *(const f32x4*)(f + 4);
    bf16x8 r;
    r[0] = (short)f2bf(a[0]); r[1] = (short)f2bf(a[1]);
    r[2] = (short)f2bf(a[2]); r[3] = (short)f2bf(a[3]);
    r[4] = (short)f2bf(b[0]); r[5] = (short)f2bf(b[1]);
    r[6] = (short)f2bf(b[2]); r[7] = (short)f2bf(b[3]);
    return r;
  };
  bf16x8 bw0[16], bw1[32];
  {
    const size_t grow = (size_t)(wid * HD + jcol);   // gate row 0..2047
#pragma unroll
    for (int kc = 0; kc < 16; ++kc)
      bw0[kc] = ldw8(p.whh0[brr], grow * 512 + kc * 32 + lk * 8);
#pragma unroll
    for (int kc = 0; kc < 16; ++kc)
      bw1[kc] = ldw8(p.wih1[brr], grow * 512 + kc * 32 + lk * 8);
#pragma unroll
    for (int kc = 16; kc < 32; ++kc)
      bw1[kc] = ldw8(p.whh1[brr], grow * 512 + (kc - 16) * 32 + lk * 8);
  }

  // ---- staging role: thread stages row rls = tid>>3; 8 chunks of 16B
  const int rls = tid >> 3;
  const int seg = tid & 7;
  const int growl = btile * 32 + rls;    // global batch row staged by this thread

  // ---- update role: threads 0..127, each owns 1 row x 4 consecutive cols
  const bool upd = (tid < 128);
  const int rl   = tid >> 2;            // local row 0..31 (for upd threads)
  const int uq4  = (tid & 3) * 4;       // col offset within jblk's 16
  const int ucol = jblk * 16 + uq4;     // global col base (4 cols)
  const int ub   = btile * 32 + rl;     // global batch row

  float bs0q[16], bs1q[16];
  if (upd) {
#pragma unroll
    for (int q = 0; q < 4; ++q)
#pragma unroll
      for (int j = 0; j < 4; ++j) {
        bs0q[q * 4 + j] = p.bsum0[brr * GG + q * HD + ucol + j];
        bs1q[q * 4 + j] = p.bsum1[brr * GG + q * HD + ucol + j];
      }
  }

  float c0[4] = {0.f, 0.f, 0.f, 0.f}, c1[4] = {0.f, 0.f, 0.f, 0.f};
  float xgc[16], xgn[16];
  unsigned int dummy = 0;

  auto xoff = [&](int t, int q) -> size_t {
    return (((size_t)brr * TT + t) * BB + ub) * GG + (size_t)q * HD + ucol;
  };
  if (upd) {
#pragma unroll
    for (int q = 0; q < 4; ++q) {
      if (XP) {
        f32x4 v = *(const f32x4*)(xpf + xoff(0, q));
#pragma unroll
        for (int j = 0; j < 4; ++j) xgc[q * 4 + j] = v[j];
      } else {
#pragma unroll
        for (int j = 0; j < 4; ++j) xgc[q * 4 + j] = bf2f(xpb[xoff(0, q) + j]);
      }
    }
  }

  // swizzled LDS fragment readers (byte ^= (row&7)<<4; write side uses same XOR)
  auto frag0 = [&](int rloc, int e0) -> bf16x8 {
    const int be = (e0 * 2) ^ ((rloc & 7) << 4);
    return *(const bf16x8*)&h0s[rloc * 512 + (be >> 1)];
  };
  auto frag1 = [&](int rloc, int e0) -> bf16x8 {
    const int be = (e0 * 2) ^ ((rloc & 7) << 4);
    return *(const bf16x8*)&h1s[rloc * 512 + (be >> 1)];
  };

  for (int s = 0; s <= TT; ++s) {
    const unsigned short* h0r = h0b + (size_t)((s + 1) & 1) * BB * HD; // h0_{s-1}
    const unsigned short* h1p = h1b + (size_t)(s & 1) * BB * HD;       // h1_{s-2}
    const bool do0 = (s < TT), do1 = (s >= 1);

    // ---- stage h tiles ONCE per block (bypass loads -> swizzled LDS; R10 schedule)
    {
      const unsigned short* s0 = h0r + (size_t)growl * HD;
      const unsigned short* s1 = h1p + (size_t)growl * HD;
      bf16x8 sv0[8], sv1[8];
#pragma unroll
      for (int c = 0; c < 8; ++c) {
        sv0[c] = ldh16(s0 + c * 64 + seg * 8);
        sv1[c] = ldh16(s1 + c * 64 + seg * 8);
      }
#pragma unroll
      for (int c = 0; c < 8; ++c) {
        const int be = ((c * 8 + seg) * 16) ^ ((rls & 7) << 4);
        *(bf16x8*)&h0s[rls * 512 + (be >> 1)] = sv0[c];
        *(bf16x8*)&h1s[rls * 512 + (be >> 1)] = sv1[c];
      }
    }

    // prefetch x_proj for next step (independent of staging)
    if (upd) {
      int tn = s + 1; if (tn > TT - 1) tn = TT - 1;
#pragma unroll
      for (int q = 0; q < 4; ++q) {
        if (XP) {
          f32x4 v = *(const f32x4*)(xpf + xoff(tn, q));
#pragma unroll
          for (int j = 0; j < 4; ++j) xgn[q * 4 + j] = v[j];
        } else {
#pragma unroll
          for (int j = 0; j < 4; ++j) xgn[q * 4 + j] = bf2f(xpb[xoff(tn, q) + j]);
        }
      }
    }
    __syncthreads();   // staged tiles visible

    if (do0) {  // layer 0, time s: P0[q] = h0_{s-1}[btile rows] @ W0[q-slice]^T
      f32x4 acc0[2];
#pragma unroll
      for (int bt = 0; bt < 2; ++bt) acc0[bt] = (f32x4){0.f, 0.f, 0.f, 0.f};
#pragma unroll
      for (int kc = 0; kc < 16; ++kc) {
        const int k0 = kc * 32 + lk * 8;
#pragma unroll
        for (int bt = 0; bt < 2; ++bt) {
          bf16x8 av = frag0(bt * 16 + l15, k0);
          acc0[bt] = __builtin_amdgcn_mfma_f32_16x16x32_bf16(av, bw0[kc], acc0[bt], 0, 0, 0);
        }
      }
#pragma unroll
      for (int bt = 0; bt < 2; ++bt)
#pragma unroll
        for (int i = 0; i < 4; ++i)
          P0[wid][bt * 16 + lk * 4 + i][l15] = acc0[bt][i];
    }
    if (do1) {  // layer 1, time s-1: P1[q] = [h0_{s-1} | h1_{s-2}] @ W1[q-slice]^T
      f32x4 acc1[2];
#pragma unroll
      for (int bt = 0; bt < 2; ++bt) acc1[bt] = (f32x4){0.f, 0.f, 0.f, 0.f};
#pragma unroll
      for (int kc = 0; kc < 32; ++kc) {
        const int k0 = kc * 32 + lk * 8;
#pragma unroll
        for (int bt = 0; bt < 2; ++bt) {
          bf16x8 av = (kc < 16) ? frag0(bt * 16 + l15, k0)
                                : frag1(bt * 16 + l15, k0 - 512);
          acc1[bt] = __builtin_amdgcn_mfma_f32_16x16x32_bf16(av, bw1[kc], acc1[bt], 0, 0, 0);
        }
      }
#pragma unroll
      for (int bt = 0; bt < 2; ++bt)
#pragma unroll
        for (int i = 0; i < 4; ++i)
          P1[wid][bt * 16 + lk * 4 + i][l15] = acc1[bt][i];
    }
    __syncthreads();

    if (do0 && upd) {  // layer-0 cell update: 1 row x 4 cols -> one 64-bit swap
      unsigned short* h0w = h0b + (size_t)(s & 1) * BB * HD;
      unsigned long long pk = 0ull;
#pragma unroll
      for (int j = 0; j < 4; ++j) {
        float gi = sigf(P0[0][rl][uq4 + j] + bs0q[0 + j] + xgc[0 + j]);
        float gf = sigf(P0[1][rl][uq4 + j] + bs0q[4 + j] + xgc[4 + j]);
        float gc = tanhf(P0[2][rl][uq4 + j] + bs0q[8 + j] + xgc[8 + j]);
        float go = sigf(P0[3][rl][uq4 + j] + bs0q[12 + j] + xgc[12 + j]);
        c0[j] = gf * c0[j] + gi * gc;
        float hv = go * tanhf(c0[j]);
        pk |= (unsigned long long)f2bf(hv) << (16 * j);
      }
      unsigned long long* dst =
          (unsigned long long*)(h0w + (size_t)ub * HD + ucol);
      unsigned long long old =
          __hip_atomic_exchange(dst, pk, __ATOMIC_RELAXED, __HIP_MEMORY_SCOPE_AGENT);
      dummy ^= (unsigned int)(old ^ (old >> 32));
    }
    if (do1 && upd) {  // layer-1 cell update + output write
      unsigned short* h1w = h1b + (size_t)((s - 1) & 1) * BB * HD;
      const int tl = s - 1;
      unsigned long long pk = 0ull;
      float hv4[4];
#pragma unroll
      for (int j = 0; j < 4; ++j) {
        float gi = sigf(P1[0][rl][uq4 + j] + bs1q[0 + j]);
        float gf = sigf(P1[1][rl][uq4 + j] + bs1q[4 + j]);
        float gc = tanhf(P1[2][rl][uq4 + j] + bs1q[8 + j]);
        float go = sigf(P1[3][rl][uq4 + j] + bs1q[12 + j]);
        c1[j] = gf * c1[j] + gi * gc;
        hv4[j] = go * tanhf(c1[j]);
        pk |= (unsigned long long)f2bf(hv4[j]) << (16 * j);
      }
      unsigned long long* dst =
          (unsigned long long*)(h1w + (size_t)ub * HD + ucol);
      unsigned long long old =
          __hip_atomic_exchange(dst, pk, __ATOMIC_RELAXED, __HIP_MEMORY_SCOPE_AGENT);
      dummy ^= (unsigned int)(old ^ (old >> 32));
      const size_t oo = (((size_t)brr * BB + ub) * TT + tl) * HD + ucol;
      if (F) {
        *(unsigned long long*)((unsigned short*)p.out + oo) = pk;
      } else {
        f32x4 v = { hv4[0], hv4[1], hv4[2], hv4[3] };
        *(f32x4*)((float*)p.out + oo) = v;
      }
    }

    if (upd) {
#pragma unroll
      for (int i2 = 0; i2 < 16; ++i2) xgc[i2] = xgn[i2];
    }

    if (s < TT) gbar_slots(slots, jblk, (unsigned int)(s + 1));
  }

  if (dummy == 0x9E3779B9u) p.bar[2047] = dummy;  // consume swap returns (never taken)
}

// ---------------- host ----------------
extern "C" void kernel_launch(void* const* d_in, const int* in_sizes, int n_in,
                              void* d_out, int out_size, void* d_ws, size_t ws_size,
                              hipStream_t stream) {
  if (n_in < 18) return;
  char* ws = (char*)d_ws;
  size_t off = 0;
  auto alloc = [&](size_t bytes) -> void* {
    off = (off + 255) & ~(size_t)255;
    void* r = ws + off;
    off += bytes;
    return r;
  };
  int* flags           = (int*)alloc(256);
  unsigned int* bar    = (unsigned int*)alloc(8192);
  int* xidx            = (int*)alloc((size_t)2 * BB * TT * 4);
  float* bsum0         = (float*)alloc((size_t)2 * GG * 4);
  float* bsum1         = (float*)alloc((size_t)2 * GG * 4);
  unsigned short* h0   = (unsigned short*)alloc((size_t)2 * 2 * BB * HD * 2);
  unsigned short* h1   = (unsigned short*)alloc((size_t)2 * 2 * BB * HD * 2);

  const size_t xp_f32_bytes = (size_t)2 * TT * BB * GG * 4;   // 67.1 MB
  const size_t xp_b16_bytes = (size_t)2 * TT * BB * GG * 2;   // 33.6 MB
  int xp32 = (off + 256 + xp_f32_bytes <= ws_size) ? 1 : 0;
  void* xp = alloc(xp32 ? xp_f32_bytes : xp_b16_bytes);
  (void)in_sizes; (void)out_size;

  lstm_detect<<<dim3(1), dim3(256), 0, stream>>>(
      (const unsigned int*)d_in[3], (const unsigned int*)d_in[0], flags);

  PrepParams pp;
  for (int i = 0; i < 18; ++i) pp.src[i] = d_in[i];
  pp.flags = flags; pp.bar = bar; pp.xidx = xidx;
  pp.bsum0 = bsum0; pp.bsum1 = bsum1;
  pp.h0 = h0; pp.h1 = h1;
  lstm_prep<<<dim3(256), dim3(256), 0, stream>>>(pp);

  GatherParams gp;
  gp.wih0[0] = d_in[2]; gp.wih0[1] = d_in[10];
  gp.xidx = xidx; gp.xp = xp; gp.flags = flags; gp.xp32 = xp32;
  lstm_gather<<<dim3(512), dim3(256), 0, stream>>>(gp);

  LstmParams lp;
  lp.xp = xp; lp.bsum0 = bsum0; lp.bsum1 = bsum1;
  lp.whh0[0] = d_in[3];  lp.whh0[1] = d_in[11];
  lp.wih1[0] = d_in[6];  lp.wih1[1] = d_in[14];
  lp.whh1[0] = d_in[7];  lp.whh1[1] = d_in[15];
  lp.h0 = h0; lp.h1 = h1;
  lp.bar = bar; lp.flags = flags; lp.xp32 = xp32; lp.out = d_out;
  lstm_main<<<dim3(NBLK), dim3(NTHR), 0, stream>>>(lp);
}

// Round 16
// 797.272 us; speedup vs baseline: 1.5361x; 1.0074x over previous
//
#include <hip/hip_runtime.h>
#include <cstdint>
#include <cstddef>

// Problem constants
#define HD 512      // hidden
#define BB 64       // batch
#define TT 64       // timesteps
#define VV 50257    // vocab
#define GG 2048     // 4*H
#define NBLK 128    // 2 branches * 2 btiles * 32 jblks (<=256 CUs -> co-resident)
#define NTHR 256    // 4 waves; wave = one GATE (q-split, register-resident weights)
#define PS 21       // P-exchange row stride (odd)
#define GCW 1024    // gather LDS chunk width (floats)
#define GR 16       // gather rows per block (64KB LDS, 2 blocks/CU; 64B stores)
#define VH 25136    // gather column-half size (2*VH >= VV)
#define SLOTSTRIDE 16  // barrier slot spacing in dwords (64B line per slot)

typedef __attribute__((ext_vector_type(8))) short bf16x8;   // 8 bf16 (4 VGPR)
typedef __attribute__((ext_vector_type(4))) float f32x4;

__device__ __forceinline__ float bf2f(unsigned short u) {
  union { unsigned int i; float f; } v; v.i = ((unsigned int)u) << 16; return v.f;
}
__device__ __forceinline__ unsigned short f2bf(float f) {
  union { float f; unsigned int i; } v; v.f = f;
  unsigned int r = (v.i + 0x7fffu + ((v.i >> 16) & 1u)) >> 16;   // RNE
  return (unsigned short)r;
}
__device__ __forceinline__ float sigf(float x) { return 1.0f / (1.0f + __expf(-x)); }

// Device-coherent 16B read (two 8B agent-scope bypass loads; proven R7-R15).
__device__ __forceinline__ bf16x8 ldh16(const unsigned short* p) {
  union { unsigned long long q[2]; bf16x8 v; } u;
  const unsigned long long* p64 = (const unsigned long long*)p;
  u.q[0] = __hip_atomic_load(p64,     __ATOMIC_RELAXED, __HIP_MEMORY_SCOPE_AGENT);
  u.q[1] = __hip_atomic_load(p64 + 1, __ATOMIC_RELAXED, __HIP_MEMORY_SCOPE_AGENT);
  return u.v;
}

// ---------------- detect: float dtype (fp32 vs bf16) and index width ----------------
__global__ void lstm_detect(const unsigned int* whh, const unsigned int* xq, int* flags) {
  __shared__ int csmall, oddnz;
  if (threadIdx.x == 0) { csmall = 0; oddnz = 0; }
  __syncthreads();
  {
    unsigned int w = whh[threadIdx.x];
    union { unsigned int i; float f; } lo; lo.i = w << 16;
    float a = fabsf(lo.f);
    if (a <= 0.0444f) atomicAdd(&csmall, 1);
  }
  if (threadIdx.x < 64) {
    if (xq[2 * threadIdx.x + 1] != 0) atomicAdd(&oddnz, 1);
  }
  __syncthreads();
  if (threadIdx.x == 0) {
    flags[0] = (csmall >= 240) ? 1 : 0;  // 1 => float inputs are bf16
    flags[1] = (oddnz == 0) ? 1 : 0;     // 1 => x is int64
  }
}

// ---------------- prep: biases, indices, h zero, barrier slots ----------------
struct PrepParams {
  const void* src[18];
  const int* flags;
  unsigned int* bar;     // 2048 uints: 4 groups x 32 slots x 16-dword stride
  int* xidx;             // [2][B*T]
  float* bsum0;          // [2][2048]
  float* bsum1;          // [2][2048]
  unsigned short* h0;    // [2][2][64][512]  bf16 ping-pong
  unsigned short* h1;    // [2][2][64][512]
};

__global__ void lstm_prep(PrepParams p) {
  const int F = p.flags[0];
  const int X = p.flags[1];
  const size_t NBS = (size_t)2 * 2 * GG;        // 8192
  const size_t NXI = (size_t)2 * BB * TT;       // 8192
  const size_t NHZ = 262144;                    // h0+h1 ushort count
  const size_t NBZ = 2048;                      // barrier slot dwords (8KB)
  const size_t TOT = NBS + NXI + NHZ + NBZ;
  for (size_t g = (size_t)blockIdx.x * blockDim.x + threadIdx.x; g < TOT;
       g += (size_t)gridDim.x * blockDim.x) {
    size_t e = g;
    if (e < NBS) {
      size_t br = e / (2 * GG), r = e % (2 * GG);
      size_t layer = r / GG, gg = r % GG;
      const void* s1 = p.src[(br ? 12 : 4) + (layer ? 4 : 0)];
      const void* s2 = p.src[(br ? 13 : 5) + (layer ? 4 : 0)];
      float v1 = F ? bf2f(((const unsigned short*)s1)[gg]) : ((const float*)s1)[gg];
      float v2 = F ? bf2f(((const unsigned short*)s2)[gg]) : ((const float*)s2)[gg];
      (layer ? p.bsum1 : p.bsum0)[br * GG + gg] = v1 + v2;
      continue;
    }
    e -= NBS;
    if (e < NXI) {
      size_t br = e / (BB * TT), r = e % (BB * TT);
      const void* s = p.src[br ? 1 : 0];
      p.xidx[e] = X ? ((const int*)s)[2 * r] : ((const int*)s)[r];
      continue;
    }
    e -= NXI;
    if (e < NHZ) {
      const size_t half = 131072;
      if (e < half) p.h0[e] = 0; else p.h1[e - half] = 0;
      continue;
    }
    e -= NHZ;
    p.bar[e] = 0;   // barrier slots reset every call (replay determinism)
  }
}

// ---------------- gather: x_proj[branch][t][b][g] = Wih0[g][ token[b,t] ] ----------
// R15 config (proven): GR=16 rows/block, 512 blocks (2/CU), one-chunk-ahead
// register prefetch, 64B-contiguous store per hit.
struct GatherParams {
  const void* wih0[2];
  const int* xidx;       // [2][4096], b-major [b][t]
  void* xp;              // [branch][t][b][g] f32 or bf16
  const int* flags;
  int xp32;
};

__launch_bounds__(256, 2)
__global__ void lstm_gather(GatherParams gp) {
  __shared__ float lds[GR][GCW];   // 64 KB
  const int tid = threadIdx.x;
  const int branch = blockIdx.x >> 8;
  const int rem = blockIdx.x & 255;
  const int gc = rem >> 1;          // 0..127
  const int half = rem & 1;
  const int g0 = gc * GR;
  const int cbase = half * VH;
  const int cend = (half ? VV : VH);
  const int F = gp.flags[0];
  const int XP = gp.xp32;
  const int t  = tid & 63;
  const int bq = tid >> 6;         // 0..3

  int tok[16];
  const int* xid = gp.xidx + branch * (BB * TT);
#pragma unroll
  for (int i = 0; i < 16; ++i) tok[i] = xid[(bq * 16 + i) * TT + t];

  float* xpf = (float*)gp.xp;
  unsigned short* xpb = (unsigned short*)gp.xp;

  float rg[GR][4];
  auto issue = [&](int c0, int cs) {
    if (F) {
      const unsigned short* w = (const unsigned short*)gp.wih0[branch];
#pragma unroll
      for (int r = 0; r < GR; ++r)
#pragma unroll
        for (int j = 0; j < 4; ++j) {
          const int c = tid + j * 256;
          rg[r][j] = (c < cs) ? bf2f(w[(size_t)(g0 + r) * VV + c0 + c]) : 0.f;
        }
    } else {
      const float* w = (const float*)gp.wih0[branch];
#pragma unroll
      for (int r = 0; r < GR; ++r)
#pragma unroll
        for (int j = 0; j < 4; ++j) {
          const int c = tid + j * 256;
          rg[r][j] = (c < cs) ? w[(size_t)(g0 + r) * VV + c0 + c] : 0.f;
        }
    }
  };

  int c0 = cbase;
  int cs = (cend - c0 < GCW) ? (cend - c0) : GCW;
  issue(c0, cs);
  for (;;) {
    // commit prefetched chunk to LDS
#pragma unroll
    for (int r = 0; r < GR; ++r)
#pragma unroll
      for (int j = 0; j < 4; ++j)
        lds[r][tid + j * 256] = rg[r][j];
    __syncthreads();

    const int c1 = c0 + GCW;
    const int cs1 = (c1 < cend) ? ((cend - c1 < GCW) ? (cend - c1) : GCW) : 0;
    if (cs1 > 0) issue(c1, cs1);   // prefetch next (hidden under scatter+sync)

    // scatter current chunk: 16 g-values -> 64B contiguous store per hit
#pragma unroll
    for (int i = 0; i < 16; ++i) {
      const unsigned int d = (unsigned int)(tok[i] - c0);
      if (d < (unsigned int)cs) {
        const int b = bq * 16 + i;
        const size_t base = (((size_t)branch * TT + t) * BB + b) * GG + g0;
        if (XP) {
#pragma unroll
          for (int v = 0; v < 4; ++v) {
            f32x4 x = { lds[v*4+0][d], lds[v*4+1][d], lds[v*4+2][d], lds[v*4+3][d] };
            *(f32x4*)(xpf + base + v * 4) = x;
          }
        } else {
#pragma unroll
          for (int r = 0; r < GR; ++r) xpb[base + r] = f2bf(lds[r][d]);
        }
      }
    }
    __syncthreads();
    if (cs1 == 0) break;
    c0 = c1; cs = cs1;
  }
}

// ---------------- slot barrier: one 64B line per block, parallel poll (proven R8-R15) ----
__device__ __forceinline__ void gbar_slots(unsigned int* slots, int myslot,
                                           unsigned int target) {
  __syncthreads();
  if (threadIdx.x < 64) {
    if (threadIdx.x == 0) {
      asm volatile("" ::: "memory");
      __hip_atomic_fetch_add(&slots[myslot * SLOTSTRIDE], 1u,
                             __ATOMIC_RELAXED, __HIP_MEMORY_SCOPE_AGENT);
    }
    const int lane = threadIdx.x;
    bool done;
    do {
      unsigned int v = target;
      if (lane < 32)
        v = __hip_atomic_load(&slots[lane * SLOTSTRIDE],
                              __ATOMIC_RELAXED, __HIP_MEMORY_SCOPE_AGENT);
      done = __all(v >= target);
      if (!done) __builtin_amdgcn_s_sleep(1);
    } while (!done);
    asm volatile("" ::: "memory");
  }
  __syncthreads();
}

// ---------------- main kernel (128 blocks co-resident) ------------------------------
// R16: sync-domain XCD locality. Each 32-block barrier group (branch,btile) is
// confined to TWO XCDs (grp = xcd>>1, member = (xcd&1)+2*slot) instead of four —
// h-swap/barrier lines have sharers on 2 dies, shortening the per-step IF chain
// if routing latency scales with sharer spread. Pure bijective relabel (G16-safe).
struct LstmParams {
  const void* xp;        // x_proj [branch][t][b][g]
  const float* bsum0;
  const float* bsum1;
  const void* whh0[2];   // [2048][512]
  const void* wih1[2];   // [2048][512]
  const void* whh1[2];   // [2048][512]
  unsigned short* h0;
  unsigned short* h1;
  unsigned int* bar;     // 4 groups x 32 slots x SLOTSTRIDE dwords
  const int* flags;
  int xp32;
  void* out;
};

__launch_bounds__(NTHR, 1)
__global__ void lstm_main(LstmParams p) {
  __shared__ float P0[4][32][PS];
  __shared__ float P1[4][32][PS];
  __shared__ __attribute__((aligned(16))) unsigned short h0s[32 * 512]; // 32 KB
  __shared__ __attribute__((aligned(16))) unsigned short h1s[32 * 512]; // 32 KB

  const int tid  = threadIdx.x;
  const int l15  = tid & 15;
  const int lk   = (tid & 63) >> 4; // k-group within wave (0..3)
  const int wid  = tid >> 6;        // wave = gate q (0..3)

  // R16 XCD-local decomposition: group (brr,btile) on 2 XCDs
  const int bid  = blockIdx.x;
  const int xcd  = bid & 7;
  const int slot = bid >> 3;                 // 0..15
  const int grp  = xcd >> 1;                 // 0..3
  const int brr  = grp >> 1;
  const int btile = grp & 1;
  const int jblk  = (xcd & 1) + 2 * slot;    // 0..31
  const int jcol  = jblk * 16 + l15;
  const int F = p.flags[0];
  const int XP = p.xp32;

  unsigned short* h0b = p.h0 + (size_t)brr * 2 * BB * HD;
  unsigned short* h1b = p.h1 + (size_t)brr * 2 * BB * HD;
  const float* xpf = (const float*)p.xp;
  const unsigned short* xpb = (const unsigned short*)p.xp;
  unsigned int* slots = p.bar + grp * 32 * SLOTSTRIDE;

  // ---- register-resident weights, loaded DIRECTLY from inputs (R13)
  auto ldw8 = [&](const void* srcp, size_t eoff) -> bf16x8 {
    if (F) return *(const bf16x8*)((const unsigned short*)srcp + eoff);
    const float* f = (const float*)srcp + eoff;
    f32x4 a = *(const f32x4*)f;
    f32x4 b = *(const f32x4*)(f + 4);
    bf16x8 r;
    r[0] = (short)f2bf(a[0]); r[1] = (short)f2bf(a[1]);
    r[2] = (short)f2bf(a[2]); r[3] = (short)f2bf(a[3]);
    r[4] = (short)f2bf(b[0]); r[5] = (short)f2bf(b[1]);
    r[6] = (short)f2bf(b[2]); r[7] = (short)f2bf(b[3]);
    return r;
  };
  bf16x8 bw0[16], bw1[32];
  {
    const size_t grow = (size_t)(wid * HD + jcol);   // gate row 0..2047
#pragma unroll
    for (int kc = 0; kc < 16; ++kc)
      bw0[kc] = ldw8(p.whh0[brr], grow * 512 + kc * 32 + lk * 8);
#pragma unroll
    for (int kc = 0; kc < 16; ++kc)
      bw1[kc] = ldw8(p.wih1[brr], grow * 512 + kc * 32 + lk * 8);
#pragma unroll
    for (int kc = 16; kc < 32; ++kc)
      bw1[kc] = ldw8(p.whh1[brr], grow * 512 + (kc - 16) * 32 + lk * 8);
  }

  // ---- staging role: thread stages row rls = tid>>3; 8 chunks of 16B
  const int rls = tid >> 3;
  const int seg = tid & 7;
  const int growl = btile * 32 + rls;    // global batch row staged by this thread

  // ---- update role: threads 0..127, each owns 1 row x 4 consecutive cols
  const bool upd = (tid < 128);
  const int rl   = tid >> 2;            // local row 0..31 (for upd threads)
  const int uq4  = (tid & 3) * 4;       // col offset within jblk's 16
  const int ucol = jblk * 16 + uq4;     // global col base (4 cols)
  const int ub   = btile * 32 + rl;     // global batch row

  float bs0q[16], bs1q[16];
  if (upd) {
#pragma unroll
    for (int q = 0; q < 4; ++q)
#pragma unroll
      for (int j = 0; j < 4; ++j) {
        bs0q[q * 4 + j] = p.bsum0[brr * GG + q * HD + ucol + j];
        bs1q[q * 4 + j] = p.bsum1[brr * GG + q * HD + ucol + j];
      }
  }

  float c0[4] = {0.f, 0.f, 0.f, 0.f}, c1[4] = {0.f, 0.f, 0.f, 0.f};
  float xgc[16], xgn[16];
  unsigned int dummy = 0;

  auto xoff = [&](int t, int q) -> size_t {
    return (((size_t)brr * TT + t) * BB + ub) * GG + (size_t)q * HD + ucol;
  };
  if (upd) {
#pragma unroll
    for (int q = 0; q < 4; ++q) {
      if (XP) {
        f32x4 v = *(const f32x4*)(xpf + xoff(0, q));
#pragma unroll
        for (int j = 0; j < 4; ++j) xgc[q * 4 + j] = v[j];
      } else {
#pragma unroll
        for (int j = 0; j < 4; ++j) xgc[q * 4 + j] = bf2f(xpb[xoff(0, q) + j]);
      }
    }
  }

  // swizzled LDS fragment readers (byte ^= (row&7)<<4; write side uses same XOR)
  auto frag0 = [&](int rloc, int e0) -> bf16x8 {
    const int be = (e0 * 2) ^ ((rloc & 7) << 4);
    return *(const bf16x8*)&h0s[rloc * 512 + (be >> 1)];
  };
  auto frag1 = [&](int rloc, int e0) -> bf16x8 {
    const int be = (e0 * 2) ^ ((rloc & 7) << 4);
    return *(const bf16x8*)&h1s[rloc * 512 + (be >> 1)];
  };

  for (int s = 0; s <= TT; ++s) {
    const unsigned short* h0r = h0b + (size_t)((s + 1) & 1) * BB * HD; // h0_{s-1}
    const unsigned short* h1p = h1b + (size_t)(s & 1) * BB * HD;       // h1_{s-2}
    const bool do0 = (s < TT), do1 = (s >= 1);

    // ---- stage h tiles ONCE per block (bypass loads -> swizzled LDS; R10 schedule)
    {
      const unsigned short* s0 = h0r + (size_t)growl * HD;
      const unsigned short* s1 = h1p + (size_t)growl * HD;
      bf16x8 sv0[8], sv1[8];
#pragma unroll
      for (int c = 0; c < 8; ++c) {
        sv0[c] = ldh16(s0 + c * 64 + seg * 8);
        sv1[c] = ldh16(s1 + c * 64 + seg * 8);
      }
#pragma unroll
      for (int c = 0; c < 8; ++c) {
        const int be = ((c * 8 + seg) * 16) ^ ((rls & 7) << 4);
        *(bf16x8*)&h0s[rls * 512 + (be >> 1)] = sv0[c];
        *(bf16x8*)&h1s[rls * 512 + (be >> 1)] = sv1[c];
      }
    }

    // prefetch x_proj for next step (independent of staging)
    if (upd) {
      int tn = s + 1; if (tn > TT - 1) tn = TT - 1;
#pragma unroll
      for (int q = 0; q < 4; ++q) {
        if (XP) {
          f32x4 v = *(const f32x4*)(xpf + xoff(tn, q));
#pragma unroll
          for (int j = 0; j < 4; ++j) xgn[q * 4 + j] = v[j];
        } else {
#pragma unroll
          for (int j = 0; j < 4; ++j) xgn[q * 4 + j] = bf2f(xpb[xoff(tn, q) + j]);
        }
      }
    }
    __syncthreads();   // staged tiles visible

    if (do0) {  // layer 0, time s: P0[q] = h0_{s-1}[btile rows] @ W0[q-slice]^T
      f32x4 acc0[2];
#pragma unroll
      for (int bt = 0; bt < 2; ++bt) acc0[bt] = (f32x4){0.f, 0.f, 0.f, 0.f};
#pragma unroll
      for (int kc = 0; kc < 16; ++kc) {
        const int k0 = kc * 32 + lk * 8;
#pragma unroll
        for (int bt = 0; bt < 2; ++bt) {
          bf16x8 av = frag0(bt * 16 + l15, k0);
          acc0[bt] = __builtin_amdgcn_mfma_f32_16x16x32_bf16(av, bw0[kc], acc0[bt], 0, 0, 0);
        }
      }
#pragma unroll
      for (int bt = 0; bt < 2; ++bt)
#pragma unroll
        for (int i = 0; i < 4; ++i)
          P0[wid][bt * 16 + lk * 4 + i][l15] = acc0[bt][i];
    }
    if (do1) {  // layer 1, time s-1: P1[q] = [h0_{s-1} | h1_{s-2}] @ W1[q-slice]^T
      f32x4 acc1[2];
#pragma unroll
      for (int bt = 0; bt < 2; ++bt) acc1[bt] = (f32x4){0.f, 0.f, 0.f, 0.f};
#pragma unroll
      for (int kc = 0; kc < 32; ++kc) {
        const int k0 = kc * 32 + lk * 8;
#pragma unroll
        for (int bt = 0; bt < 2; ++bt) {
          bf16x8 av = (kc < 16) ? frag0(bt * 16 + l15, k0)
                                : frag1(bt * 16 + l15, k0 - 512);
          acc1[bt] = __builtin_amdgcn_mfma_f32_16x16x32_bf16(av, bw1[kc], acc1[bt], 0, 0, 0);
        }
      }
#pragma unroll
      for (int bt = 0; bt < 2; ++bt)
#pragma unroll
        for (int i = 0; i < 4; ++i)
          P1[wid][bt * 16 + lk * 4 + i][l15] = acc1[bt][i];
    }
    __syncthreads();

    if (do0 && upd) {  // layer-0 cell update: 1 row x 4 cols -> one 64-bit swap
      unsigned short* h0w = h0b + (size_t)(s & 1) * BB * HD;
      unsigned long long pk = 0ull;
#pragma unroll
      for (int j = 0; j < 4; ++j) {
        float gi = sigf(P0[0][rl][uq4 + j] + bs0q[0 + j] + xgc[0 + j]);
        float gf = sigf(P0[1][rl][uq4 + j] + bs0q[4 + j] + xgc[4 + j]);
        float gc = tanhf(P0[2][rl][uq4 + j] + bs0q[8 + j] + xgc[8 + j]);
        float go = sigf(P0[3][rl][uq4 + j] + bs0q[12 + j] + xgc[12 + j]);
        c0[j] = gf * c0[j] + gi * gc;
        float hv = go * tanhf(c0[j]);
        pk |= (unsigned long long)f2bf(hv) << (16 * j);
      }
      unsigned long long* dst =
          (unsigned long long*)(h0w + (size_t)ub * HD + ucol);
      unsigned long long old =
          __hip_atomic_exchange(dst, pk, __ATOMIC_RELAXED, __HIP_MEMORY_SCOPE_AGENT);
      dummy ^= (unsigned int)(old ^ (old >> 32));
    }
    if (do1 && upd) {  // layer-1 cell update + output write
      unsigned short* h1w = h1b + (size_t)((s - 1) & 1) * BB * HD;
      const int tl = s - 1;
      unsigned long long pk = 0ull;
      float hv4[4];
#pragma unroll
      for (int j = 0; j < 4; ++j) {
        float gi = sigf(P1[0][rl][uq4 + j] + bs1q[0 + j]);
        float gf = sigf(P1[1][rl][uq4 + j] + bs1q[4 + j]);
        float gc = tanhf(P1[2][rl][uq4 + j] + bs1q[8 + j]);
        float go = sigf(P1[3][rl][uq4 + j] + bs1q[12 + j]);
        c1[j] = gf * c1[j] + gi * gc;
        hv4[j] = go * tanhf(c1[j]);
        pk |= (unsigned long long)f2bf(hv4[j]) << (16 * j);
      }
      unsigned long long* dst =
          (unsigned long long*)(h1w + (size_t)ub * HD + ucol);
      unsigned long long old =
          __hip_atomic_exchange(dst, pk, __ATOMIC_RELAXED, __HIP_MEMORY_SCOPE_AGENT);
      dummy ^= (unsigned int)(old ^ (old >> 32));
      const size_t oo = (((size_t)brr * BB + ub) * TT + tl) * HD + ucol;
      if (F) {
        *(unsigned long long*)((unsigned short*)p.out + oo) = pk;
      } else {
        f32x4 v = { hv4[0], hv4[1], hv4[2], hv4[3] };
        *(f32x4*)((float*)p.out + oo) = v;
      }
    }

    if (upd) {
#pragma unroll
      for (int i2 = 0; i2 < 16; ++i2) xgc[i2] = xgn[i2];
    }

    if (s < TT) gbar_slots(slots, jblk, (unsigned int)(s + 1));
  }

  if (dummy == 0x9E3779B9u) p.bar[2047] = dummy;  // consume swap returns (never taken)
}

// ---------------- host ----------------
extern "C" void kernel_launch(void* const* d_in, const int* in_sizes, int n_in,
                              void* d_out, int out_size, void* d_ws, size_t ws_size,
                              hipStream_t stream) {
  if (n_in < 18) return;
  char* ws = (char*)d_ws;
  size_t off = 0;
  auto alloc = [&](size_t bytes) -> void* {
    off = (off + 255) & ~(size_t)255;
    void* r = ws + off;
    off += bytes;
    return r;
  };
  int* flags           = (int*)alloc(256);
  unsigned int* bar    = (unsigned int*)alloc(8192);
  int* xidx            = (int*)alloc((size_t)2 * BB * TT * 4);
  float* bsum0         = (float*)alloc((size_t)2 * GG * 4);
  float* bsum1         = (float*)alloc((size_t)2 * GG * 4);
  unsigned short* h0   = (unsigned short*)alloc((size_t)2 * 2 * BB * HD * 2);
  unsigned short* h1   = (unsigned short*)alloc((size_t)2 * 2 * BB * HD * 2);

  const size_t xp_f32_bytes = (size_t)2 * TT * BB * GG * 4;   // 67.1 MB
  const size_t xp_b16_bytes = (size_t)2 * TT * BB * GG * 2;   // 33.6 MB
  int xp32 = (off + 256 + xp_f32_bytes <= ws_size) ? 1 : 0;
  void* xp = alloc(xp32 ? xp_f32_bytes : xp_b16_bytes);
  (void)in_sizes; (void)out_size;

  lstm_detect<<<dim3(1), dim3(256), 0, stream>>>(
      (const unsigned int*)d_in[3], (const unsigned int*)d_in[0], flags);

  PrepParams pp;
  for (int i = 0; i < 18; ++i) pp.src[i] = d_in[i];
  pp.flags = flags; pp.bar = bar; pp.xidx = xidx;
  pp.bsum0 = bsum0; pp.bsum1 = bsum1;
  pp.h0 = h0; pp.h1 = h1;
  lstm_prep<<<dim3(256), dim3(256), 0, stream>>>(pp);

  GatherParams gp;
  gp.wih0[0] = d_in[2]; gp.wih0[1] = d_in[10];
  gp.xidx = xidx; gp.xp = xp; gp.flags = flags; gp.xp32 = xp32;
  lstm_gather<<<dim3(512), dim3(256), 0, stream>>>(gp);

  LstmParams lp;
  lp.xp = xp; lp.bsum0 = bsum0; lp.bsum1 = bsum1;
  lp.whh0[0] = d_in[3];  lp.whh0[1] = d_in[11];
  lp.wih1[0] = d_in[6];  lp.wih1[1] = d_in[14];
  lp.whh1[0] = d_in[7];  lp.whh1[1] = d_in[15];
  lp.h0 = h0; lp.h1 = h1;
  lp.bar = bar; lp.flags = flags; lp.xp32 = xp32; lp.out = d_out;
  lstm_main<<<dim3(NBLK), dim3(NTHR), 0, stream>>>(lp);
}